// Round 1
// baseline (871.257 us; speedup 1.0000x reference)
//
#include <hip/hip_runtime.h>

#define IMG_H 512
#define IMG_W 512
#define WOUT  256          // output cols per block
#define WV    272          // WOUT + 16 halo cols
#define NR    20           // circular input row slots (16 halo + 4 step rows)
#define RS    4            // rows per step
#define C1F   1.0e-4f
#define C2F   9.0e-4f

// ---------------------------------------------------------------------------
// prep: extract exact separable 1D weights from the 2D filters.
// g2d[i][j] == v[i]*v[j] with v[j] = g[h][j]/sqrt(g[h][h])  (outer product).
// ws layout (floats): [0..4]=w5, [8..18]=w11, [32..48]=w17
// ---------------------------------------------------------------------------
__global__ void prep_weights_kernel(const float* __restrict__ g0,
                                    const float* __restrict__ g1,
                                    const float* __restrict__ g2,
                                    float* __restrict__ ws) {
  if (blockIdx.x == 0 && threadIdx.x == 0) {
    const float* gs[3] = {g0, g1, g2};
    const int ks[3]  = {5, 11, 17};
    const int off[3] = {0, 8, 32};
    for (int s = 0; s < 3; ++s) {
      const float* g = gs[s];
      int k = ks[s], h = k / 2;
      double rs = 1.0 / sqrt((double)g[h * k + h]);
      for (int j = 0; j < k; ++j)
        ws[off[s] + j] = (float)((double)g[h * k + j] * rs);
    }
  }
}

__device__ __forceinline__ float to_sgpr(float x) {
  int i = __builtin_amdgcn_readfirstlane(__builtin_bit_cast(int, x));
  return __builtin_bit_cast(float, i);
}

__device__ __forceinline__ int mod20(int x) {  // valid for 0 <= x < ~300000
  return x - 20 * ((x * 3277) >> 16);
}

// stage NROWS rows (global rows gr0..gr0+NROWS-1) into circular buffer.
// sin_ layout: [slot][2][WV] floats, de-interleaved b1/b2 planes.
template<int NROWS>
__device__ __forceinline__ void stage_rows(const float* __restrict__ p1,
                                           const float* __restrict__ p2,
                                           float* __restrict__ sin_,
                                           int gr0, int x0, int tid) {
  constexpr int NT = NROWS * WV;
  for (int idx = tid; idx < NT; idx += 256) {
    int rr = ((idx >> 4) * 3856) >> 16;   // idx / 272  (== (idx/16)/17)
    int cc = idx - rr * WV;
    int gr = gr0 + rr;
    int gc = x0 - 8 + cc;
    float v1 = 0.f, v2 = 0.f;
    if ((unsigned)gr < (unsigned)IMG_H && (unsigned)gc < (unsigned)IMG_W) {
      int o = gr * IMG_W + gc;
      v1 = p1[o];
      v2 = p2[o];
    }
    int slot = mod20(gr + 48);            // slot(gr) = (gr+8) mod 20
    float* p = sin_ + slot * (WV * 2) + cc;
    p[0]  = v1;
    p[WV] = v2;
  }
}

// vertical pass: one (row r, 4-col group g) task; products recomputed from
// b1/b2 so only 2 float4 LDS reads per tap row.
// sv_ layout: [5 planes][RS rows][WV cols]
template<int K>
__device__ __forceinline__ void v_col(const float (&wk)[K],
                                      const float* __restrict__ sin_,
                                      float* __restrict__ sv_,
                                      int yc, int r, int g) {
  constexpr int HK = K / 2;
  float a0[4] = {0,0,0,0}, a1[4] = {0,0,0,0}, a2[4] = {0,0,0,0},
        a3[4] = {0,0,0,0}, a4[4] = {0,0,0,0};
  int slot = mod20(yc + r - HK + 48);
  const int cb = 4 * g;
  #pragma unroll
  for (int t = 0; t < K; ++t) {
    const float* row = sin_ + slot * (WV * 2) + cb;
    float4 A = *(const float4*)(row);        // b1, cols 4g..4g+3
    float4 B = *(const float4*)(row + WV);   // b2, cols 4g..4g+3
    float w = wk[t];
    a0[0] = fmaf(w, A.x,        a0[0]);
    a1[0] = fmaf(w, B.x,        a1[0]);
    a2[0] = fmaf(w, A.x * A.x,  a2[0]);
    a3[0] = fmaf(w, B.x * B.x,  a3[0]);
    a4[0] = fmaf(w, A.x * B.x,  a4[0]);
    a0[1] = fmaf(w, A.y,        a0[1]);
    a1[1] = fmaf(w, B.y,        a1[1]);
    a2[1] = fmaf(w, A.y * A.y,  a2[1]);
    a3[1] = fmaf(w, B.y * B.y,  a3[1]);
    a4[1] = fmaf(w, A.y * B.y,  a4[1]);
    a0[2] = fmaf(w, A.z,        a0[2]);
    a1[2] = fmaf(w, B.z,        a1[2]);
    a2[2] = fmaf(w, A.z * A.z,  a2[2]);
    a3[2] = fmaf(w, B.z * B.z,  a3[2]);
    a4[2] = fmaf(w, A.z * B.z,  a4[2]);
    a0[3] = fmaf(w, A.w,        a0[3]);
    a1[3] = fmaf(w, B.w,        a1[3]);
    a2[3] = fmaf(w, A.w * A.w,  a2[3]);
    a3[3] = fmaf(w, B.w * B.w,  a3[3]);
    a4[3] = fmaf(w, A.w * B.w,  a4[3]);
    slot++;
    if (slot == NR) slot = 0;
  }
  float* vb = sv_ + r * WV + cb;
  *(float4*)(vb + 0 * RS * WV) = make_float4(a0[0], a0[1], a0[2], a0[3]);
  *(float4*)(vb + 1 * RS * WV) = make_float4(a1[0], a1[1], a1[2], a1[3]);
  *(float4*)(vb + 2 * RS * WV) = make_float4(a2[0], a2[1], a2[2], a2[3]);
  *(float4*)(vb + 3 * RS * WV) = make_float4(a3[0], a3[1], a3[2], a3[3]);
  *(float4*)(vb + 4 * RS * WV) = make_float4(a4[0], a4[1], a4[2], a4[3]);
}

// horizontal pass + partial ssim for one (row r, 4-col group g).
template<int K>
__device__ __forceinline__ void h_col(const float (&wk)[K],
                                      const float* __restrict__ sv_,
                                      int r, int g, float (&accs)[4]) {
  constexpr int OFF = 8 - K / 2;
  float conv[5][4];
  #pragma unroll
  for (int d = 0; d < 5; ++d) {
    const float* vb = sv_ + (d * RS + r) * WV + 4 * g;
    float win[20];
    if constexpr (K == 5) {
      #pragma unroll
      for (int q = 1; q < 4; ++q) {
        float4 t = *(const float4*)(vb + 4 * q);
        win[4*q+0] = t.x; win[4*q+1] = t.y; win[4*q+2] = t.z; win[4*q+3] = t.w;
      }
    } else {
      #pragma unroll
      for (int q = 0; q < 5; ++q) {
        float4 t = *(const float4*)(vb + 4 * q);
        win[4*q+0] = t.x; win[4*q+1] = t.y; win[4*q+2] = t.z; win[4*q+3] = t.w;
      }
    }
    #pragma unroll
    for (int j = 0; j < 4; ++j) {
      float s = 0.f;
      #pragma unroll
      for (int t = 0; t < K; ++t) s = fmaf(wk[t], win[j + t + OFF], s);
      conv[d][j] = s;
    }
  }
  #pragma unroll
  for (int j = 0; j < 4; ++j) {
    float mu1 = conv[0][j], mu2 = conv[1][j];
    float s11 = conv[2][j], s22 = conv[3][j], s12 = conv[4][j];
    float mu11 = mu1 * mu1, mu22 = mu2 * mu2, mu12 = mu1 * mu2;
    float sg1  = fabsf(s11 - mu11);
    float sg2  = fabsf(s22 - mu22);
    float sg12 = s12 - mu12;
    float num  = fmaf(2.f, mu12, C1F) * fmaf(2.f, sg12, C2F);
    float den  = (mu11 + mu22 + C1F) * (sg1 + sg2 + C2F);
    float ssim = __fdividef(num, den);
    accs[j] += fminf(1.f, fmaxf(-1.f, ssim));
  }
}

// ---------------------------------------------------------------------------
// main fused kernel: grid = 96 images * 8 row-strips * 2 col-blocks = 1536
// block = 256 threads; LDS = 43520 (input) + 21760 (V planes) = 63.75 KB
//   -> 2 blocks/CU (8 waves/CU)
// ---------------------------------------------------------------------------
__global__ __launch_bounds__(256, 2)
void mssim_kernel(const float* __restrict__ b1, const float* __restrict__ b2,
                  const float* __restrict__ ws, float* __restrict__ out) {
  __shared__ __attribute__((aligned(16))) float sin_[NR * WV * 2];
  __shared__ __attribute__((aligned(16))) float sv_[5 * RS * WV];

  const int tid = threadIdx.x;
  const int bid = blockIdx.x;
  const int img = bid >> 4;
  const int rem = bid & 15;
  const int y0  = (rem >> 1) * 64;
  const int x0  = (rem & 1) * WOUT;
  const float* p1 = b1 + img * (IMG_H * IMG_W);
  const float* p2 = b2 + img * (IMG_H * IMG_W);
  float*       po = out + img * (IMG_H * IMG_W);

  // weights -> SGPRs (single scalar operand per FMA)
  float w17[17], w11[11], w5[5];
  #pragma unroll
  for (int i = 0; i < 17; ++i) w17[i] = to_sgpr(ws[32 + i]);
  #pragma unroll
  for (int i = 0; i < 11; ++i) w11[i] = to_sgpr(ws[8 + i]);
  #pragma unroll
  for (int i = 0; i < 5;  ++i) w5[i]  = to_sgpr(ws[i]);

  // preload halo rows y0-8 .. y0+7
  stage_rows<16>(p1, p2, sin_, y0 - 8, x0, tid);

  const int vr = tid >> 6;            // row within step
  const int vg = tid & 63;            // 4-col group 0..63
  const int er = tid & 3;             // extra halo-group task (tid < 16)
  const int eg = 64 + (tid >> 2);     // groups 64..67
  const bool extra = tid < 16;

  #pragma unroll 1
  for (int step = 0; step < 16; ++step) {
    const int yc = y0 + step * RS;
    stage_rows<4>(p1, p2, sin_, yc + 8, x0, tid);   // rows yc+8..yc+11
    __syncthreads();

    float accs[4] = {0.f, 0.f, 0.f, 0.f};

    v_col<17>(w17, sin_, sv_, yc, vr, vg);
    if (extra) v_col<17>(w17, sin_, sv_, yc, er, eg);
    __syncthreads();
    h_col<17>(w17, sv_, vr, vg, accs);
    __syncthreads();

    v_col<11>(w11, sin_, sv_, yc, vr, vg);
    if (extra) v_col<11>(w11, sin_, sv_, yc, er, eg);
    __syncthreads();
    h_col<11>(w11, sv_, vr, vg, accs);
    __syncthreads();

    v_col<5>(w5, sin_, sv_, yc, vr, vg);
    if (extra) v_col<5>(w5, sin_, sv_, yc, er, eg);
    __syncthreads();
    h_col<5>(w5, sv_, vr, vg, accs);
    __syncthreads();

    // out = 1 - ((sum_s (1-(clip_s+1)/2))/3 + 1)/2  ==  0.25 + sum(clip_s)/12
    float4 o = make_float4(0.25f + accs[0] * (1.f / 12.f),
                           0.25f + accs[1] * (1.f / 12.f),
                           0.25f + accs[2] * (1.f / 12.f),
                           0.25f + accs[3] * (1.f / 12.f));
    *(float4*)(po + (yc + vr) * IMG_W + x0 + 4 * vg) = o;
  }
}

extern "C" void kernel_launch(void* const* d_in, const int* in_sizes, int n_in,
                              void* d_out, int out_size, void* d_ws, size_t ws_size,
                              hipStream_t stream) {
  const float* b1 = (const float*)d_in[0];
  const float* b2 = (const float*)d_in[1];
  const float* g0 = (const float*)d_in[2];
  const float* g1 = (const float*)d_in[3];
  const float* g2 = (const float*)d_in[4];
  float* ws  = (float*)d_ws;
  float* out = (float*)d_out;

  prep_weights_kernel<<<1, 64, 0, stream>>>(g0, g1, g2, ws);
  mssim_kernel<<<1536, 256, 0, stream>>>(b1, b2, ws, out);
}

// Round 2
// 702.615 us; speedup vs baseline: 1.2400x; 1.2400x over previous
//
#include <hip/hip_runtime.h>

#define IMG_H 512
#define IMG_W 512
#define WOUT  128          // output cols per block
#define WV    144          // WOUT + 16 halo cols
#define NRING 24           // circular input row slots (16 halo + 8 step rows)
#define RS    8            // rows per step
#define NSTEP 8            // steps per block (64-row strip)
#define C1F   1.0e-4f
#define C2F   9.0e-4f

// ---------------------------------------------------------------------------
// prep: extract exact separable 1D weights from the 2D filters.
// g2d[i][j] == v[i]*v[j] with v[j] = g[h][j]/sqrt(g[h][h])  (outer product).
// ws layout (floats): [0..4]=w5, [8..18]=w11, [32..48]=w17
// ---------------------------------------------------------------------------
__global__ void prep_weights_kernel(const float* __restrict__ g0,
                                    const float* __restrict__ g1,
                                    const float* __restrict__ g2,
                                    float* __restrict__ ws) {
  if (blockIdx.x == 0 && threadIdx.x == 0) {
    const float* gs[3] = {g0, g1, g2};
    const int ks[3]  = {5, 11, 17};
    const int off[3] = {0, 8, 32};
    for (int s = 0; s < 3; ++s) {
      const float* g = gs[s];
      int k = ks[s], h = k / 2;
      double rs = 1.0 / sqrt((double)g[h * k + h]);
      for (int j = 0; j < k; ++j)
        ws[off[s] + j] = (float)((double)g[h * k + j] * rs);
    }
  }
}

__device__ __forceinline__ float to_sgpr(float x) {
  int i = __builtin_amdgcn_readfirstlane(__builtin_bit_cast(int, x));
  return __builtin_bit_cast(float, i);
}

__device__ __forceinline__ int mod24(int x) {  // valid for 0 <= x < ~1500
  return x - 24 * ((x * 2731) >> 16);
}

// stage NROWS rows (global rows gr0..gr0+NROWS-1) into circular buffer.
// sin_ layout: [slot][2][WV] floats, de-interleaved b1/b2 planes.
// slot(row r) = (r + 8) mod 24
template<int NROWS>
__device__ __forceinline__ void stage_rows(const float* __restrict__ p1,
                                           const float* __restrict__ p2,
                                           float* __restrict__ sin_,
                                           int gr0, int x0, int tid) {
  constexpr int NT = NROWS * WV;
  for (int idx = tid; idx < NT; idx += 256) {
    int rr = ((idx >> 4) * 7282) >> 16;   // idx / 144  (== (idx/16)/9)
    int cc = idx - rr * WV;
    int gr = gr0 + rr;
    int gc = x0 - 8 + cc;
    float v1 = 0.f, v2 = 0.f;
    if ((unsigned)gr < (unsigned)IMG_H && (unsigned)gc < (unsigned)IMG_W) {
      int o = gr * IMG_W + gc;
      v1 = p1[o];
      v2 = p2[o];
    }
    int slot = mod24(gr + 56);            // == (gr+8) mod 24, gr >= -8
    float* p = sin_ + slot * (WV * 2) + cc;
    p[0]  = v1;
    p[WV] = v2;
  }
}

// vertical pass for task t in [0, RS*WV/4): rr = t/36 (row in step),
// cc = t%36 (float4 col group). Products recomputed from b1/b2 so only
// 2 float4 LDS reads per tap row.  sv_ layout: [5 planes][RS rows][WV cols]
template<int K>
__device__ __forceinline__ void v_col(const float (&wk)[K],
                                      const float* __restrict__ sin_,
                                      float* __restrict__ sv_,
                                      int yc, int t) {
  constexpr int HK = K / 2;
  int rr = (t * 1821) >> 16;              // t / 36, valid t < 288
  int cc = t - rr * 36;
  float a0[4] = {0,0,0,0}, a1[4] = {0,0,0,0}, a2[4] = {0,0,0,0},
        a3[4] = {0,0,0,0}, a4[4] = {0,0,0,0};
  int slot = mod24(yc + rr - HK + 56);
  const int cb = 4 * cc;
  #pragma unroll
  for (int tap = 0; tap < K; ++tap) {
    const float* row = sin_ + slot * (WV * 2) + cb;
    float4 A = *(const float4*)(row);        // b1, 4 cols
    float4 B = *(const float4*)(row + WV);   // b2, 4 cols
    float w = wk[tap];
    a0[0] = fmaf(w, A.x,        a0[0]);
    a1[0] = fmaf(w, B.x,        a1[0]);
    a2[0] = fmaf(w, A.x * A.x,  a2[0]);
    a3[0] = fmaf(w, B.x * B.x,  a3[0]);
    a4[0] = fmaf(w, A.x * B.x,  a4[0]);
    a0[1] = fmaf(w, A.y,        a0[1]);
    a1[1] = fmaf(w, B.y,        a1[1]);
    a2[1] = fmaf(w, A.y * A.y,  a2[1]);
    a3[1] = fmaf(w, B.y * B.y,  a3[1]);
    a4[1] = fmaf(w, A.y * B.y,  a4[1]);
    a0[2] = fmaf(w, A.z,        a0[2]);
    a1[2] = fmaf(w, B.z,        a1[2]);
    a2[2] = fmaf(w, A.z * A.z,  a2[2]);
    a3[2] = fmaf(w, B.z * B.z,  a3[2]);
    a4[2] = fmaf(w, A.z * B.z,  a4[2]);
    a0[3] = fmaf(w, A.w,        a0[3]);
    a1[3] = fmaf(w, B.w,        a1[3]);
    a2[3] = fmaf(w, A.w * A.w,  a2[3]);
    a3[3] = fmaf(w, B.w * B.w,  a3[3]);
    a4[3] = fmaf(w, A.w * B.w,  a4[3]);
    slot++;
    if (slot == NRING) slot = 0;
  }
  float* vb = sv_ + rr * WV + cb;
  constexpr int PS = RS * WV;              // plane stride
  *(float4*)(vb + 0 * PS) = make_float4(a0[0], a0[1], a0[2], a0[3]);
  *(float4*)(vb + 1 * PS) = make_float4(a1[0], a1[1], a1[2], a1[3]);
  *(float4*)(vb + 2 * PS) = make_float4(a2[0], a2[1], a2[2], a2[3]);
  *(float4*)(vb + 3 * PS) = make_float4(a3[0], a3[1], a3[2], a3[3]);
  *(float4*)(vb + 4 * PS) = make_float4(a4[0], a4[1], a4[2], a4[3]);
}

// horizontal pass + partial ssim for (row rr, 4-col group g).
template<int K>
__device__ __forceinline__ void h_col(const float (&wk)[K],
                                      const float* __restrict__ sv_,
                                      int rr, int g, float (&accs)[4]) {
  constexpr int OFF = 8 - K / 2;
  float conv[5][4];
  #pragma unroll
  for (int d = 0; d < 5; ++d) {
    const float* vb = sv_ + (d * RS + rr) * WV + 4 * g;
    float win[20];
    if constexpr (K == 5) {
      #pragma unroll
      for (int q = 1; q < 4; ++q) {
        float4 t = *(const float4*)(vb + 4 * q);
        win[4*q+0] = t.x; win[4*q+1] = t.y; win[4*q+2] = t.z; win[4*q+3] = t.w;
      }
    } else {
      #pragma unroll
      for (int q = 0; q < 5; ++q) {
        float4 t = *(const float4*)(vb + 4 * q);
        win[4*q+0] = t.x; win[4*q+1] = t.y; win[4*q+2] = t.z; win[4*q+3] = t.w;
      }
    }
    #pragma unroll
    for (int j = 0; j < 4; ++j) {
      float s = 0.f;
      #pragma unroll
      for (int t = 0; t < K; ++t) s = fmaf(wk[t], win[j + t + OFF], s);
      conv[d][j] = s;
    }
  }
  #pragma unroll
  for (int j = 0; j < 4; ++j) {
    float mu1 = conv[0][j], mu2 = conv[1][j];
    float s11 = conv[2][j], s22 = conv[3][j], s12 = conv[4][j];
    float mu11 = mu1 * mu1, mu22 = mu2 * mu2, mu12 = mu1 * mu2;
    float sg1  = fabsf(s11 - mu11);
    float sg2  = fabsf(s22 - mu22);
    float sg12 = s12 - mu12;
    float num  = fmaf(2.f, mu12, C1F) * fmaf(2.f, sg12, C2F);
    float den  = (mu11 + mu22 + C1F) * (sg1 + sg2 + C2F);
    float ssim = __fdividef(num, den);
    accs[j] += fminf(1.f, fmaxf(-1.f, ssim));
  }
}

// ---------------------------------------------------------------------------
// main fused kernel: grid = 96 images * 8 row-strips * 4 col-blocks = 3072
// block = 256 threads; LDS = 27648 (input ring) + 23040 (V planes) = 49.5 KB
//   -> 3 blocks/CU (12 waves/CU); 7 barriers per 8-row step (0.875/row)
// ---------------------------------------------------------------------------
__global__ __launch_bounds__(256, 3)
void mssim_kernel(const float* __restrict__ b1, const float* __restrict__ b2,
                  const float* __restrict__ ws, float* __restrict__ out) {
  __shared__ __attribute__((aligned(16))) float sin_[NRING * WV * 2];
  __shared__ __attribute__((aligned(16))) float sv_[5 * RS * WV];

  const int tid = threadIdx.x;
  const int bid = blockIdx.x;
  const int img = bid >> 5;
  const int rem = bid & 31;
  const int y0  = (rem >> 2) * (RS * NSTEP);
  const int x0  = (rem & 3) * WOUT;
  const float* p1 = b1 + img * (IMG_H * IMG_W);
  const float* p2 = b2 + img * (IMG_H * IMG_W);
  float*       po = out + img * (IMG_H * IMG_W);

  // weights -> SGPRs (single scalar operand per FMA)
  float w17[17], w11[11], w5[5];
  #pragma unroll
  for (int i = 0; i < 17; ++i) w17[i] = to_sgpr(ws[32 + i]);
  #pragma unroll
  for (int i = 0; i < 11; ++i) w11[i] = to_sgpr(ws[8 + i]);
  #pragma unroll
  for (int i = 0; i < 5;  ++i) w5[i]  = to_sgpr(ws[i]);

  // preload halo rows y0-8 .. y0+7
  stage_rows<16>(p1, p2, sin_, y0 - 8, x0, tid);

  const int hr = tid >> 5;            // H row within step (0..7)
  const int hg = tid & 31;            // H 4-col group (0..31)
  const bool extra = tid >= 224;      // V overflow tasks 256..287 -> wave 3

  #pragma unroll 1
  for (int step = 0; step < NSTEP; ++step) {
    const int yc = y0 + step * RS;
    stage_rows<RS>(p1, p2, sin_, yc + 8, x0, tid);  // rows yc+8..yc+15
    __syncthreads();

    float accs[4] = {0.f, 0.f, 0.f, 0.f};

    v_col<17>(w17, sin_, sv_, yc, tid);
    if (extra) v_col<17>(w17, sin_, sv_, yc, tid + 32);
    __syncthreads();
    h_col<17>(w17, sv_, hr, hg, accs);
    __syncthreads();

    v_col<11>(w11, sin_, sv_, yc, tid);
    if (extra) v_col<11>(w11, sin_, sv_, yc, tid + 32);
    __syncthreads();
    h_col<11>(w11, sv_, hr, hg, accs);
    __syncthreads();

    v_col<5>(w5, sin_, sv_, yc, tid);
    if (extra) v_col<5>(w5, sin_, sv_, yc, tid + 32);
    __syncthreads();
    h_col<5>(w5, sv_, hr, hg, accs);
    __syncthreads();

    // out = 1 - ((sum_s (1-(clip_s+1)/2))/3 + 1)/2  ==  0.25 + sum(clip_s)/12
    float4 o = make_float4(0.25f + accs[0] * (1.f / 12.f),
                           0.25f + accs[1] * (1.f / 12.f),
                           0.25f + accs[2] * (1.f / 12.f),
                           0.25f + accs[3] * (1.f / 12.f));
    *(float4*)(po + (yc + hr) * IMG_W + x0 + 4 * hg) = o;
  }
}

extern "C" void kernel_launch(void* const* d_in, const int* in_sizes, int n_in,
                              void* d_out, int out_size, void* d_ws, size_t ws_size,
                              hipStream_t stream) {
  const float* b1 = (const float*)d_in[0];
  const float* b2 = (const float*)d_in[1];
  const float* g0 = (const float*)d_in[2];
  const float* g1 = (const float*)d_in[3];
  const float* g2 = (const float*)d_in[4];
  float* ws  = (float*)d_ws;
  float* out = (float*)d_out;

  prep_weights_kernel<<<1, 64, 0, stream>>>(g0, g1, g2, ws);
  mssim_kernel<<<3072, 256, 0, stream>>>(b1, b2, ws, out);
}